// Round 2
// baseline (613.431 us; speedup 1.0000x reference)
//
#include <hip/hip_runtime.h>

#define SEQ 600
#define PP 6
#define TOUT 594   // SEQ - PP

// ---------------- Kernel A: per-row AR(6) fit + x_hat ----------------
// One wave (64 lanes) per row; block = 256 threads = 4 rows.
__global__ __launch_bounds__(256) void ar_fit_kernel(
    const float* __restrict__ x,
    float* __restrict__ x_hat,
    float* __restrict__ wout)     // 8 floats per row (w0..w6, pad)
{
    __shared__ __align__(16) float sxr[4][608];   // row + 8 zero pad

    const int wave = threadIdx.x >> 6;
    const int lane = threadIdx.x & 63;
    const int row  = (blockIdx.x << 2) + wave;

    // ---- stage row into LDS (coalesced float4) ----
    {
        const float4* xr = reinterpret_cast<const float4*>(x + (size_t)row * SEQ);
        float4* s4 = reinterpret_cast<float4*>(sxr[wave]);
        for (int i = lane; i < SEQ / 4; i += 64) s4[i] = xr[i];
        if (lane < 8) sxr[wave][SEQ + lane] = 0.0f;
    }
    __syncthreads();

    const float* sx = sxr[wave];
    float w[7];

    // ---- accumulate S = sum x, Q[d] = sum x[i]*x[i+d], d=0..6 ----
    float S = 0.f;
    float Q[7] = {0.f, 0.f, 0.f, 0.f, 0.f, 0.f, 0.f};
    for (int i = lane; i < SEQ; i += 64) {
        float x0 = sx[i];
        S += x0;
        #pragma unroll
        for (int d = 0; d < 7; ++d) Q[d] += x0 * sx[i + d];
    }
    // butterfly reduce 8 values across the wave
    #pragma unroll
    for (int m = 1; m < 64; m <<= 1) {
        S += __shfl_xor(S, m, 64);
        #pragma unroll
        for (int d = 0; d < 7; ++d) Q[d] += __shfl_xor(Q[d], m, 64);
    }

    // ---- boundary prefix/suffix sums (uniform broadcast LDS reads) ----
    float pre[8], suf[8];
    pre[0] = 0.f; suf[0] = 0.f;
    #pragma unroll
    for (int c = 1; c < 8; ++c) {
        pre[c] = pre[c - 1] + sx[c - 1];
        suf[c] = suf[c - 1] + sx[SEQ - c];
    }

    // ---- reconstruct normal equations G (7x7) and rhs (7) ----
    // D[t] = (1, x[t+5], x[t+4], ..., x[t]),  y[t] = x[t+6],  t = 0..593
    float M[7][7];
    float rhs[7];
    M[0][0] = (float)TOUT;
    #pragma unroll
    for (int k = 0; k < 6; ++k) {
        float v = S - pre[5 - k] - suf[k + 1];
        M[0][k + 1] = v; M[k + 1][0] = v;
    }
    #pragma unroll
    for (int k = 0; k < 6; ++k) {
        #pragma unroll
        for (int l = k; l < 6; ++l) {
            const int a = 5 - l, d = l - k;
            float head = 0.f;
            #pragma unroll
            for (int i = 0; i < a; ++i) head += sx[i] * sx[i + d];
            float tail = 0.f;
            #pragma unroll
            for (int i = a + TOUT; i < SEQ; ++i) tail += sx[i] * sx[i + d];
            float v = Q[d] - head - tail;
            M[k + 1][l + 1] = v; M[l + 1][k + 1] = v;
        }
    }
    rhs[0] = S - pre[6];
    #pragma unroll
    for (int k = 0; k < 6; ++k) {
        const int a = 5 - k, d = k + 1;
        float head = 0.f;
        #pragma unroll
        for (int i = 0; i < a; ++i) head += sx[i] * sx[i + d];
        float tail = 0.f;
        #pragma unroll
        for (int i = a + TOUT; i < SEQ; ++i) tail += sx[i] * sx[i + d];
        rhs[k + 1] = Q[d] - head - tail;
    }

    // ---- Cholesky solve (SPD, cond ~ O(1)); redundant per-lane ----
    #pragma unroll
    for (int j = 0; j < 7; ++j) {
        float s = M[j][j];
        #pragma unroll
        for (int m = 0; m < j; ++m) s -= M[j][m] * M[j][m];
        float ljj = sqrtf(s);
        M[j][j] = ljj;
        float inv = 1.0f / ljj;
        #pragma unroll
        for (int i2 = j + 1; i2 < 7; ++i2) {
            float s2 = M[i2][j];
            #pragma unroll
            for (int m = 0; m < j; ++m) s2 -= M[i2][m] * M[j][m];
            M[i2][j] = s2 * inv;
        }
    }
    float z[7];
    #pragma unroll
    for (int i2 = 0; i2 < 7; ++i2) {
        float s = rhs[i2];
        #pragma unroll
        for (int m = 0; m < i2; ++m) s -= M[i2][m] * z[m];
        z[i2] = s / M[i2][i2];
    }
    #pragma unroll
    for (int i2 = 6; i2 >= 0; --i2) {
        float s = z[i2];
        #pragma unroll
        for (int m = i2 + 1; m < 7; ++m) s -= M[m][i2] * w[m];
        w[i2] = s / M[i2][i2];
    }

    // ---- write w (lane 0, two float4 stores, constant indexing) ----
    if (lane == 0) {
        float4* wo = reinterpret_cast<float4*>(wout + (size_t)row * 8);
        float4 a = make_float4(w[0], w[1], w[2], w[3]);
        float4 b = make_float4(w[4], w[5], w[6], 0.f);
        wo[0] = a;
        wo[1] = b;
    }

    // ---- x_hat: 0 for t<6, else AR prediction; float4 stores ----
    {
        float4* xh4 = reinterpret_cast<float4*>(x_hat + (size_t)row * SEQ);
        for (int i = lane; i < SEQ / 4; i += 64) {
            float4 v;
            float* vp = reinterpret_cast<float*>(&v);
            #pragma unroll
            for (int c = 0; c < 4; ++c) {
                int e = 4 * i + c;
                float p = 0.f;
                if (e >= PP) {
                    p = w[0];
                    #pragma unroll
                    for (int k = 1; k <= 6; ++k) p += w[k] * sx[e - k];
                }
                vp[c] = p;
            }
            xh4[i] = v;
        }
    }
}

// ---------------- Kernel B: pure streaming coeffs broadcast ----------------
// One block (256 threads) per row; writes 900 float4 = 14.4 KB coalesced.
__global__ __launch_bounds__(256) void coeff_fill_kernel(
    const float* __restrict__ wout,
    float* __restrict__ coeffs)
{
    const int row = blockIdx.x;
    const int t   = threadIdx.x;

    const float* wr = wout + (size_t)row * 8;
    const float w1 = wr[1], w2 = wr[2], w3 = wr[3];
    const float w4 = wr[4], w5 = wr[5], w6 = wr[6];

    // repeating 12-float pattern as three float4 phases
    const float4 P0 = make_float4(w1, w2, w3, w4);
    const float4 P1 = make_float4(w5, w6, w1, w2);
    const float4 P2 = make_float4(w3, w4, w5, w6);

    float4* out = reinterpret_cast<float4*>(coeffs + (size_t)row * (SEQ * PP));

    int r = t % 3;                      // phase for i = t (256 ≡ 1 mod 3)
    #pragma unroll
    for (int j = 0; j < 4; ++j) {
        const int i = t + 256 * j;      // float4 index within row, < 900
        if (i < (SEQ * PP) / 4) {
            float4 v = (r == 0) ? P0 : ((r == 1) ? P1 : P2);
            if (i < 9) {                // flat idx 4i+c < 36  <=>  t < 6 → zero
                float* vp = reinterpret_cast<float*>(&v);
                #pragma unroll
                for (int c = 0; c < 4; ++c)
                    if (4 * i + c < PP * PP) vp[c] = 0.f;
            }
            out[i] = v;
        }
        r = (r == 2) ? 0 : (r + 1);
    }
}

extern "C" void kernel_launch(void* const* d_in, const int* in_sizes, int n_in,
                              void* d_out, int out_size, void* d_ws, size_t ws_size,
                              hipStream_t stream) {
    const float* x = (const float*)d_in[0];
    const int N = in_sizes[0] / SEQ;           // 32768

    float* out    = (float*)d_out;
    float* coeffs = out;                                        // N*600*6
    float* extra  = out + (size_t)N * SEQ * PP;                 // p_logits (N*5) + p_hard (N)
    float* x_hat  = extra + (size_t)N * 6;                      // N*600
    float* wbuf   = (float*)d_ws;                               // N*8 floats

    // p_logits and p_hard are all zeros (0 bit pattern valid for f32 and i32)
    hipMemsetAsync(extra, 0, (size_t)N * 6 * sizeof(float), stream);

    ar_fit_kernel<<<dim3(N / 4), dim3(256), 0, stream>>>(x, x_hat, wbuf);
    coeff_fill_kernel<<<dim3(N), dim3(256), 0, stream>>>(wbuf, coeffs);
}

// Round 4
// 598.658 us; speedup vs baseline: 1.0247x; 1.0247x over previous
//
#include <hip/hip_runtime.h>

#define SEQ 600
#define PP 6
#define TOUT 594        // SEQ - PP
#define NF4 150         // float4s per row
#define NF4P 152        // padded (8 zero floats)

typedef float v4f __attribute__((ext_vector_type(4)));

__device__ __forceinline__ void nt_store4(float4* p, float4 v) {
    v4f vv;
    vv.x = v.x; vv.y = v.y; vv.z = v.z; vv.w = v.w;
    __builtin_nontemporal_store(vv, reinterpret_cast<v4f*>(p));
}

// One wave per row; block = 256 = 4 rows; grid = N/4.
__global__ __launch_bounds__(256) void ar_all_kernel(
    const float* __restrict__ x,
    float* __restrict__ coeffs,
    float* __restrict__ extra,    // p_logits (N*5) then p_hard (N)
    float* __restrict__ x_hat,
    int N)
{
    __shared__ __align__(16) float4 sxr[4][NF4P];

    const int wave = threadIdx.x >> 6;
    const int lane = threadIdx.x & 63;
    const int row  = (blockIdx.x << 2) + wave;

    float4* s4 = sxr[wave];

    // ---- stage row into LDS (float4, coalesced) + zero pad ----
    {
        const float4* xr = reinterpret_cast<const float4*>(x + (size_t)row * SEQ);
        float4 r0, r1, r2;
        int m0 = lane, m1 = lane + 64, m2 = lane + 128;
        r0 = xr[m0];
        r1 = xr[m1];
        if (m2 < NF4) r2 = xr[m2];
        s4[m0] = r0;
        s4[m1] = r1;
        if (m2 < NF4) s4[m2] = r2;
        if (lane < 2) s4[NF4 + lane] = make_float4(0.f, 0.f, 0.f, 0.f);
    }
    __syncthreads();

    // ---- Q[d] = sum_i x[i]*x[i+d] (zero-padded), S = sum x; b128 windows ----
    float S = 0.f;
    float Q[7] = {0.f, 0.f, 0.f, 0.f, 0.f, 0.f, 0.f};
    #pragma unroll
    for (int k = 0; k < 3; ++k) {
        const int m = lane + 64 * k;
        if (m < NF4) {
            float4 a = s4[m], b = s4[m + 1], c = s4[m + 2];
            float W[12] = {a.x, a.y, a.z, a.w, b.x, b.y, b.z, b.w,
                           c.x, c.y, c.z, c.w};
            #pragma unroll
            for (int cc = 0; cc < 4; ++cc) {
                S += W[cc];
                #pragma unroll
                for (int d = 0; d < 7; ++d) Q[d] += W[cc] * W[cc + d];
            }
        }
    }
    // butterfly reduce 8 values across the wave
    #pragma unroll
    for (int m = 1; m < 64; m <<= 1) {
        S += __shfl_xor(S, m, 64);
        #pragma unroll
        for (int d = 0; d < 7; ++d) Q[d] += __shfl_xor(Q[d], m, 64);
    }

    // ---- boundary values via 6 uniform b128 reads ----
    float low[8], hig[16];
    {
        float4 e0 = s4[0], e1 = s4[1];
        float4 t0 = s4[148], t1 = s4[149], t2 = s4[150], t3 = s4[151];
        low[0]=e0.x; low[1]=e0.y; low[2]=e0.z; low[3]=e0.w;
        low[4]=e1.x; low[5]=e1.y; low[6]=e1.z; low[7]=e1.w;
        hig[0]=t0.x; hig[1]=t0.y; hig[2]=t0.z; hig[3]=t0.w;      // sx[592..595]
        hig[4]=t1.x; hig[5]=t1.y; hig[6]=t1.z; hig[7]=t1.w;      // sx[596..599]
        hig[8]=t2.x; hig[9]=t2.y; hig[10]=t2.z; hig[11]=t2.w;    // pad zeros
        hig[12]=t3.x; hig[13]=t3.y; hig[14]=t3.z; hig[15]=t3.w;
    }
    float pre[8], suf[8];
    pre[0] = 0.f; suf[0] = 0.f;
    #pragma unroll
    for (int c = 1; c < 8; ++c) {
        pre[c] = pre[c - 1] + low[c - 1];
        suf[c] = suf[c - 1] + hig[8 - c];      // sx[600-c]
    }

    // ---- normal equations G (7x7) and rhs ----
    float M[7][7];
    float rhs[7];
    M[0][0] = (float)TOUT;
    #pragma unroll
    for (int k = 0; k < 6; ++k) {
        float v = S - pre[5 - k] - suf[k + 1];
        M[k + 1][0] = v; M[0][k + 1] = v;
    }
    #pragma unroll
    for (int k = 0; k < 6; ++k) {
        #pragma unroll
        for (int l = k; l < 6; ++l) {
            const int a = 5 - l, d = l - k;
            float head = 0.f;
            #pragma unroll
            for (int i = 0; i < a; ++i) head += low[i] * low[i + d];
            float tail = 0.f;
            #pragma unroll
            for (int i = a + TOUT; i < SEQ; ++i)
                tail += hig[i - 592] * hig[i + d - 592];
            float v = Q[d] - head - tail;
            M[l + 1][k + 1] = v; M[k + 1][l + 1] = v;
        }
    }
    rhs[0] = S - pre[6];
    #pragma unroll
    for (int k = 0; k < 6; ++k) {
        const int a = 5 - k, d = k + 1;
        float head = 0.f;
        #pragma unroll
        for (int i = 0; i < a; ++i) head += low[i] * low[i + d];
        float tail = 0.f;
        #pragma unroll
        for (int i = a + TOUT; i < SEQ; ++i)
            tail += hig[i - 592] * hig[i + d - 592];
        rhs[k + 1] = Q[d] - head - tail;
    }

    // ---- Cholesky (SPD) with rcp-based inverse diag; redundant per-lane ----
    float invd[7];
    #pragma unroll
    for (int j = 0; j < 7; ++j) {
        float s = M[j][j];
        #pragma unroll
        for (int m = 0; m < j; ++m) s -= M[j][m] * M[j][m];
        float ljj = sqrtf(s);
        M[j][j] = ljj;
        float inv = __builtin_amdgcn_rcpf(ljj);
        invd[j] = inv;
        #pragma unroll
        for (int i2 = j + 1; i2 < 7; ++i2) {
            float s2 = M[i2][j];
            #pragma unroll
            for (int m = 0; m < j; ++m) s2 -= M[i2][m] * M[j][m];
            M[i2][j] = s2 * inv;
        }
    }
    float w[7], z[7];
    #pragma unroll
    for (int i2 = 0; i2 < 7; ++i2) {
        float s = rhs[i2];
        #pragma unroll
        for (int m = 0; m < i2; ++m) s -= M[i2][m] * z[m];
        z[i2] = s * invd[i2];
    }
    #pragma unroll
    for (int i2 = 6; i2 >= 0; --i2) {
        float s = z[i2];
        #pragma unroll
        for (int m = i2 + 1; m < 7; ++m) s -= M[m][i2] * w[m];
        w[i2] = s * invd[i2];
    }

    // ---- p_logits / p_hard zeros (int 0 == float 0.0f bit pattern) ----
    if (lane < 5) extra[(size_t)5 * row + lane] = 0.f;
    if (lane == 5) extra[(size_t)5 * N + row] = 0.f;

    // ---- coeffs: 900 float4/row; per-lane pre-rotated 12-float pattern ----
    {
        const float4 P0 = make_float4(w[1], w[2], w[3], w[4]);
        const float4 P1 = make_float4(w[5], w[6], w[1], w[2]);
        const float4 P2 = make_float4(w[3], w[4], w[5], w[6]);
        const int r0 = lane % 3;        // phase of float4 index i = lane
        const float4 A0 = (r0 == 0) ? P0 : ((r0 == 1) ? P1 : P2);
        const float4 A1 = (r0 == 0) ? P1 : ((r0 == 1) ? P2 : P0);
        const float4 A2 = (r0 == 0) ? P2 : ((r0 == 1) ? P0 : P1);

        float4* crow = reinterpret_cast<float4*>(coeffs + (size_t)row * (SEQ * PP));
        // j=0: float4 indices < 9 (flat < 36, i.e. t < 6) are zero
        float4 v0 = (lane <= 8) ? make_float4(0.f, 0.f, 0.f, 0.f) : A0;
        nt_store4(crow + lane, v0);
        #pragma unroll
        for (int j = 1; j < 14; ++j) {
            const float4 v = (j % 3 == 0) ? A0 : ((j % 3 == 1) ? A1 : A2);
            nt_store4(crow + lane + 64 * j, v);
        }
        if (lane < 4) nt_store4(crow + lane + 64 * 14, A2);   // i=896..899, 14%3==2
    }

    // ---- x_hat: b128 windows; t<6 -> 0 ----
    {
        float4* xh4 = reinterpret_cast<float4*>(x_hat + (size_t)row * SEQ);
        #pragma unroll
        for (int k = 0; k < 3; ++k) {
            const int m = lane + 64 * k;
            if (m < NF4) {
                float4 v;
                if (m == 0) {
                    v = make_float4(0.f, 0.f, 0.f, 0.f);
                } else {
                    const int mm2 = (m >= 2) ? (m - 2) : 0;   // clamp; W[0..3] unused when m==1
                    float4 ra = s4[mm2], rb = s4[m - 1], rc = s4[m];
                    float W[12] = {ra.x, ra.y, ra.z, ra.w, rb.x, rb.y, rb.z, rb.w,
                                   rc.x, rc.y, rc.z, rc.w};   // W[j] = sx[4m-8+j]
                    float p[4];
                    #pragma unroll
                    for (int c = 0; c < 4; ++c) {
                        float s = w[0];
                        #pragma unroll
                        for (int kk = 1; kk <= 6; ++kk) s += w[kk] * W[8 + c - kk];
                        p[c] = s;
                    }
                    if (m == 1) { p[0] = 0.f; p[1] = 0.f; }   // e=4,5 < PP
                    v = make_float4(p[0], p[1], p[2], p[3]);
                }
                nt_store4(xh4 + m, v);
            }
        }
    }
}

extern "C" void kernel_launch(void* const* d_in, const int* in_sizes, int n_in,
                              void* d_out, int out_size, void* d_ws, size_t ws_size,
                              hipStream_t stream) {
    const float* x = (const float*)d_in[0];
    const int N = in_sizes[0] / SEQ;           // 32768

    float* out    = (float*)d_out;
    float* coeffs = out;                                 // N*600*6
    float* extra  = out + (size_t)N * SEQ * PP;          // p_logits (N*5) + p_hard (N)
    float* x_hat  = extra + (size_t)N * 6;               // N*600

    ar_all_kernel<<<dim3(N / 4), dim3(256), 0, stream>>>(x, coeffs, extra, x_hat, N);
}

// Round 5
// 593.293 us; speedup vs baseline: 1.0339x; 1.0090x over previous
//
#include <hip/hip_runtime.h>

#define SEQ 600
#define PP 6
#define TOUT 594        // SEQ - PP
#define NF4 150         // float4s per row
#define NF4P 152        // padded (8 zero floats)

typedef float v4f __attribute__((ext_vector_type(4)));

// ---- DPP wave-64 sum (canonical gfx9 sequence, VALU-only) ----
template<int CTRL>
__device__ __forceinline__ float dpp_mov(float v) {
    return __int_as_float(__builtin_amdgcn_update_dpp(
        0, __float_as_int(v), CTRL, 0xF, 0xF, true));   // bound_ctrl: zero-fill
}
__device__ __forceinline__ float wave_sum(float v) {
    v += dpp_mov<0x111>(v);   // row_shr:1
    v += dpp_mov<0x112>(v);   // row_shr:2
    v += dpp_mov<0x114>(v);   // row_shr:4
    v += dpp_mov<0x118>(v);   // row_shr:8
    v += dpp_mov<0x142>(v);   // row_bcast:15
    v += dpp_mov<0x143>(v);   // row_bcast:31
    return __int_as_float(__builtin_amdgcn_readlane(__float_as_int(v), 63));
}

// One wave per row; block = 256 = 4 rows; grid = N/4.
__global__ __launch_bounds__(256) void ar_all_kernel(
    const float* __restrict__ x,
    float* __restrict__ coeffs,
    float* __restrict__ extra,    // p_logits (N*5) then p_hard (N)
    float* __restrict__ x_hat,
    int N)
{
    __shared__ __align__(16) v4f sxr[4][NF4P];

    const int wave = threadIdx.x >> 6;
    const int lane = threadIdx.x & 63;
    const int row  = (blockIdx.x << 2) + wave;

    v4f* s4 = sxr[wave];

    // ---- stage row into LDS (nontemporal float4 loads, coalesced) + zero pad ----
    {
        const v4f* xr = reinterpret_cast<const v4f*>(x + (size_t)row * SEQ);
        v4f r0 = __builtin_nontemporal_load(xr + lane);
        v4f r1 = __builtin_nontemporal_load(xr + lane + 64);
        v4f r2;
        const int m2 = lane + 128;
        if (m2 < NF4) r2 = __builtin_nontemporal_load(xr + m2);
        s4[lane] = r0;
        s4[lane + 64] = r1;
        if (m2 < NF4) s4[m2] = r2;
        if (lane < 2) { v4f z = {0.f, 0.f, 0.f, 0.f}; s4[NF4 + lane] = z; }
    }
    __syncthreads();

    // ---- Q[d] = sum_i x[i]*x[i+d] (zero-padded), S = sum x; b128 windows ----
    float S = 0.f;
    float Q[7] = {0.f, 0.f, 0.f, 0.f, 0.f, 0.f, 0.f};
    #pragma unroll
    for (int k = 0; k < 3; ++k) {
        const int m = lane + 64 * k;
        if (m < NF4) {
            v4f a = s4[m], b = s4[m + 1], c = s4[m + 2];
            float W[12] = {a.x, a.y, a.z, a.w, b.x, b.y, b.z, b.w,
                           c.x, c.y, c.z, c.w};
            #pragma unroll
            for (int cc = 0; cc < 4; ++cc) {
                S += W[cc];
                #pragma unroll
                for (int d = 0; d < 7; ++d) Q[d] += W[cc] * W[cc + d];
            }
        }
    }
    // VALU-only wave reduction (replaces 48 ds_swizzle, ~700-cyc chain)
    S = wave_sum(S);
    #pragma unroll
    for (int d = 0; d < 7; ++d) Q[d] = wave_sum(Q[d]);

    // ---- boundary values via 4 uniform b128 reads (pads are known zero) ----
    float low[8], hig[8];
    {
        v4f e0 = s4[0], e1 = s4[1];
        v4f t0 = s4[148], t1 = s4[149];
        low[0]=e0.x; low[1]=e0.y; low[2]=e0.z; low[3]=e0.w;
        low[4]=e1.x; low[5]=e1.y; low[6]=e1.z; low[7]=e1.w;
        hig[0]=t0.x; hig[1]=t0.y; hig[2]=t0.z; hig[3]=t0.w;   // sx[592..595]
        hig[4]=t1.x; hig[5]=t1.y; hig[6]=t1.z; hig[7]=t1.w;   // sx[596..599]
    }
    float pre[8], suf[8];
    pre[0] = 0.f; suf[0] = 0.f;
    #pragma unroll
    for (int c = 1; c < 8; ++c) {
        pre[c] = pre[c - 1] + low[c - 1];
        suf[c] = suf[c - 1] + hig[8 - c];      // sx[600-c]
    }

    // ---- normal equations G (7x7) and rhs ----
    // Window sum C(a,d) = sum_{i=a}^{a+593} x[i]x[i+d] = Q[d] - head - tail,
    // tail terms with i+d >= 600 are identically zero (pad) -> skipped.
    float M[7][7];
    float rhs[7];
    M[0][0] = (float)TOUT;
    #pragma unroll
    for (int k = 0; k < 6; ++k) {
        float v = S - pre[5 - k] - suf[k + 1];
        M[k + 1][0] = v; M[0][k + 1] = v;
    }
    #pragma unroll
    for (int k = 0; k < 6; ++k) {
        #pragma unroll
        for (int l = k; l < 6; ++l) {
            const int a = 5 - l, d = l - k;
            float head = 0.f;
            #pragma unroll
            for (int i = 0; i < a; ++i) head += low[i] * low[i + d];
            float tail = 0.f;
            #pragma unroll
            for (int i = a + TOUT; i < SEQ; ++i)
                if (i + d < SEQ) tail += hig[i - 592] * hig[i + d - 592];
            float v = Q[d] - head - tail;
            M[l + 1][k + 1] = v; M[k + 1][l + 1] = v;
        }
    }
    rhs[0] = S - pre[6];
    #pragma unroll
    for (int k = 0; k < 6; ++k) {
        const int a = 5 - k, d = k + 1;
        float head = 0.f;
        #pragma unroll
        for (int i = 0; i < a; ++i) head += low[i] * low[i + d];
        float tail = 0.f;
        #pragma unroll
        for (int i = a + TOUT; i < SEQ; ++i)
            if (i + d < SEQ) tail += hig[i - 592] * hig[i + d - 592];
        rhs[k + 1] = Q[d] - head - tail;
    }

    // ---- Cholesky (SPD) with rcp-based inverse diag; redundant per-lane ----
    float invd[7];
    #pragma unroll
    for (int j = 0; j < 7; ++j) {
        float s = M[j][j];
        #pragma unroll
        for (int m = 0; m < j; ++m) s -= M[j][m] * M[j][m];
        float ljj = sqrtf(s);
        M[j][j] = ljj;
        float inv = __builtin_amdgcn_rcpf(ljj);
        invd[j] = inv;
        #pragma unroll
        for (int i2 = j + 1; i2 < 7; ++i2) {
            float s2 = M[i2][j];
            #pragma unroll
            for (int m = 0; m < j; ++m) s2 -= M[i2][m] * M[j][m];
            M[i2][j] = s2 * inv;
        }
    }
    float w[7], z[7];
    #pragma unroll
    for (int i2 = 0; i2 < 7; ++i2) {
        float s = rhs[i2];
        #pragma unroll
        for (int m = 0; m < i2; ++m) s -= M[i2][m] * z[m];
        z[i2] = s * invd[i2];
    }
    #pragma unroll
    for (int i2 = 6; i2 >= 0; --i2) {
        float s = z[i2];
        #pragma unroll
        for (int m = i2 + 1; m < 7; ++m) s -= M[m][i2] * w[m];
        w[i2] = s * invd[i2];
    }

    // ---- coeffs: 900 float4/row; per-lane pre-rotated 12-float pattern ----
    {
        const v4f P0 = {w[1], w[2], w[3], w[4]};
        const v4f P1 = {w[5], w[6], w[1], w[2]};
        const v4f P2 = {w[3], w[4], w[5], w[6]};
        const int r0 = lane % 3;        // phase of float4 index i = lane
        const v4f A0 = (r0 == 0) ? P0 : ((r0 == 1) ? P1 : P2);
        const v4f A1 = (r0 == 0) ? P1 : ((r0 == 1) ? P2 : P0);
        const v4f A2 = (r0 == 0) ? P2 : ((r0 == 1) ? P0 : P1);

        v4f* crow = reinterpret_cast<v4f*>(coeffs + (size_t)row * (SEQ * PP));
        // j=0: float4 indices < 9 (flat < 36, i.e. t < 6) are zero
        v4f zz = {0.f, 0.f, 0.f, 0.f};
        crow[lane] = (lane <= 8) ? zz : A0;
        #pragma unroll
        for (int j = 1; j < 14; ++j) {
            crow[lane + 64 * j] = (j % 3 == 0) ? A0 : ((j % 3 == 1) ? A1 : A2);
        }
        if (lane < 4) crow[lane + 64 * 14] = A2;   // i=896..899, phase 2
    }

    // ---- x_hat: b128 windows; t<6 -> 0 ----
    {
        v4f* xh4 = reinterpret_cast<v4f*>(x_hat + (size_t)row * SEQ);
        #pragma unroll
        for (int k = 0; k < 3; ++k) {
            const int m = lane + 64 * k;
            if (m < NF4) {
                v4f v;
                if (m == 0) {
                    v4f zz = {0.f, 0.f, 0.f, 0.f};
                    v = zz;
                } else {
                    const int mm2 = (m >= 2) ? (m - 2) : 0;   // clamp; W[0..3] unused when m==1
                    v4f ra = s4[mm2], rb = s4[m - 1], rc = s4[m];
                    float W[12] = {ra.x, ra.y, ra.z, ra.w, rb.x, rb.y, rb.z, rb.w,
                                   rc.x, rc.y, rc.z, rc.w};   // W[j] = sx[4m-8+j]
                    float p[4];
                    #pragma unroll
                    for (int c = 0; c < 4; ++c) {
                        float s = w[0];
                        #pragma unroll
                        for (int kk = 1; kk <= 6; ++kk) s += w[kk] * W[8 + c - kk];
                        p[c] = s;
                    }
                    if (m == 1) { p[0] = 0.f; p[1] = 0.f; }   // e=4,5 < PP
                    v.x = p[0]; v.y = p[1]; v.z = p[2]; v.w = p[3];
                }
                xh4[m] = v;
            }
        }
    }

    // ---- p_logits / p_hard zeros (int 0 == float 0.0f bit pattern) ----
    if (lane < 5) extra[(size_t)5 * row + lane] = 0.f;
    if (lane == 5) extra[(size_t)5 * N + row] = 0.f;
}

extern "C" void kernel_launch(void* const* d_in, const int* in_sizes, int n_in,
                              void* d_out, int out_size, void* d_ws, size_t ws_size,
                              hipStream_t stream) {
    const float* x = (const float*)d_in[0];
    const int N = in_sizes[0] / SEQ;           // 32768

    float* out    = (float*)d_out;
    float* coeffs = out;                                 // N*600*6
    float* extra  = out + (size_t)N * SEQ * PP;          // p_logits (N*5) + p_hard (N)
    float* x_hat  = extra + (size_t)N * 6;               // N*600

    ar_all_kernel<<<dim3(N / 4), dim3(256), 0, stream>>>(x, coeffs, extra, x_hat, N);
}